// Round 10
// baseline (1885.502 us; speedup 1.0000x reference)
//
#include <hip/hip_runtime.h>
#include <hip/hip_bf16.h>
#include <math.h>

#define Bb 64
#define Tt 1024
#define Dd 128
#define Hh 256
#define G4 1024  // 4*H
#define Vv 128
#define NVh 3
#define BT (Bb*Tt)

typedef __fp16 half2_t __attribute__((ext_vector_type(2)));
typedef __fp16 f16x4 __attribute__((ext_vector_type(4)));
typedef __fp16 f16x8 __attribute__((ext_vector_type(8)));
typedef float f32x4 __attribute__((ext_vector_type(4)));

__device__ __forceinline__ half2_t pkh(float a, float b) {
    return __builtin_amdgcn_cvt_pkrtz(a, b);
}
__device__ __forceinline__ float fdot2(half2_t a, half2_t b, float c) {
#if __has_builtin(__builtin_amdgcn_fdot2)
    return __builtin_amdgcn_fdot2(a, b, c, false);
#else
    return c + (float)a[0] * (float)b[0] + (float)a[1] * (float)b[1];
#endif
}
__device__ __forceinline__ half2_t bch(unsigned int x) {
    return __builtin_bit_cast(half2_t, x);
}
__device__ __forceinline__ unsigned int bcu(half2_t x) {
    return __builtin_bit_cast(unsigned int, x);
}
__device__ __forceinline__ float fsig(float x) {
    return __builtin_amdgcn_rcpf(1.f + __expf(-x));
}
__device__ __forceinline__ float ftanh(float x) {
    float e = __expf(-2.f * fabsf(x));
    float r = (1.f - e) * __builtin_amdgcn_rcpf(1.f + e);
    return copysignf(r, x);
}
// pack 8 consecutive f32 into f16x8 fragment
__device__ __forceinline__ f16x8 pk8(const float* p) {
    float4 a = *(const float4*)p;
    float4 b = *(const float4*)(p + 4);
    uint4 u;
    u.x = bcu(pkh(a.x, a.y));
    u.y = bcu(pkh(a.z, a.w));
    u.z = bcu(pkh(b.x, b.y));
    u.w = bcu(pkh(b.z, b.w));
    return __builtin_bit_cast(f16x8, u);
}

// ---------------- Kernel 0: f32 -> f16 convert (RNE), n multiple of 4 ----------
__global__ __launch_bounds__(256) void cvt16(const float* __restrict__ in,
                                             __fp16* __restrict__ out, int n4) {
    int i = blockIdx.x * 256 + threadIdx.x;
    if (i < n4) {
        float4 v = ((const float4*)in)[i];
        f16x4 o;
        o[0] = (__fp16)v.x; o[1] = (__fp16)v.y;
        o[2] = (__fp16)v.z; o[3] = (__fp16)v.w;
        ((f16x4*)out)[i] = o;
    }
}

// ---------------- Kernel A: gx via MFMA f16, fused f32->f16 cvt ------------------
// gx2[bt][jj][gate] (f16x4 packed) = x[bt][:]·W_ih[gate*256+jj][:] + b_ih + b_hh
__global__ __launch_bounds__(256) void gx_mfma(const float* __restrict__ x,
                                               const float* __restrict__ Wih,
                                               const float* __restrict__ bih,
                                               const float* __restrict__ bhh,
                                               __fp16* __restrict__ gx2) {
    const int tid = threadIdx.x;
    const int w = tid >> 6, l = tid & 63;
    const int mb = blockIdx.x * 64 + w * 16;
    const int jj0 = blockIdx.y * 16;
    const int lr = l & 15, lk = l >> 4;

    f32x4 acc[4] = {};
    const float* xa = x + (size_t)(mb + lr) * Dd + lk * 8;
    #pragma unroll
    for (int ks = 0; ks < 4; ++ks) {                 // K=128, 32 per step
        f16x8 af = pk8(xa + ks * 32);
        #pragma unroll
        for (int g = 0; g < 4; ++g) {
            const float* bb = Wih + (size_t)(g * 256 + jj0 + lr) * Dd + ks * 32 + lk * 8;
            f16x8 bf = pk8(bb);
            acc[g] = __builtin_amdgcn_mfma_f32_16x16x32_f16(af, bf, acc[g], 0, 0, 0);
        }
    }
    float bsum[4];
    #pragma unroll
    for (int g = 0; g < 4; ++g) {
        int j = g * 256 + jj0 + lr;
        bsum[g] = bih[j] + bhh[j];
    }
    #pragma unroll
    for (int r = 0; r < 4; ++r) {
        int m = mb + lk * 4 + r;                     // D row = (lane>>4)*4+reg
        f16x4 o;
        o[0] = (__fp16)(acc[0][r] + bsum[0]);
        o[1] = (__fp16)(acc[1][r] + bsum[1]);
        o[2] = (__fp16)(acc[2][r] + bsum[2]);
        o[3] = (__fp16)(acc[3][r] + bsum[3]);
        *(f16x4*)&gx2[((size_t)m * Hh + jj0 + lr) * 4] = o;
    }
}

// ---------------- Kernel B: persistent LSTM scan (v9) ----------------------------
// R8 structure (512 thr, S=2 K-split), gate-o tail shrunk: 224 reg-pairs/thread.
// Thread (jj=tid&255, s=tid>>8) owns all 4 gate rows of h-index jj, K-half s:
//   gates i,f,g : w[3][64] = 192 pairs in regs
//   gate  o     : pairs [0,32) in wo[32] regs; pairs [32,64) in 64KB LDS (8 b128)
// LDS ops/thread/step: 16 h-broadcast + 8 W-tail + ~1 exchange (was 32+).
__global__ __launch_bounds__(512, 2) void lstm_scan(const __fp16* __restrict__ gx2,
                                                    const float* __restrict__ Whh,
                                                    __fp16* __restrict__ hs16) {
    __shared__ __align__(16) uint4 wlds[8 * 512];    // 64KB: [q][tid]
    __shared__ __align__(16) __fp16 hsh[Hh];         // 512B
    __shared__ __align__(16) float4 pex[256];        // 4KB: s=1 partials
    const int tid = threadIdx.x;
    const int jj = tid & 255;
    const int s = tid >> 8;            // wave-uniform (waves 0-3: s=0, 4-7: s=1)
    const int b = blockIdx.x;

    // ---- stage W: gates i,f,g K-half s into regs; gate o: 32 pairs regs + 32 LDS ----
    half2_t w[3][64];
    half2_t wo[32];
    #pragma unroll
    for (int g = 0; g < 3; ++g) {
        const float* wr = Whh + (size_t)(g * 256 + jj) * Hh + s * 128;
        #pragma unroll
        for (int c = 0; c < 16; ++c) {
            float4 f0 = *(const float4*)&wr[c * 8];
            float4 f1 = *(const float4*)&wr[c * 8 + 4];
            w[g][c*4+0] = pkh(f0.x, f0.y);
            w[g][c*4+1] = pkh(f0.z, f0.w);
            w[g][c*4+2] = pkh(f1.x, f1.y);
            w[g][c*4+3] = pkh(f1.z, f1.w);
        }
    }
    {
        const float* wr3 = Whh + (size_t)(3 * 256 + jj) * Hh + s * 128;
        #pragma unroll
        for (int c = 0; c < 8; ++c) {          // pairs 0..31 -> regs
            float4 f0 = *(const float4*)&wr3[c * 8];
            float4 f1 = *(const float4*)&wr3[c * 8 + 4];
            wo[c*4+0] = pkh(f0.x, f0.y);
            wo[c*4+1] = pkh(f0.z, f0.w);
            wo[c*4+2] = pkh(f1.x, f1.y);
            wo[c*4+3] = pkh(f1.z, f1.w);
        }
        #pragma unroll
        for (int q = 0; q < 8; ++q) {          // pairs 32..63 -> LDS
            float4 f0 = *(const float4*)&wr3[64 + q * 8];
            float4 f1 = *(const float4*)&wr3[64 + q * 8 + 4];
            uint4 o;
            o.x = bcu(pkh(f0.x, f0.y));
            o.y = bcu(pkh(f0.z, f0.w));
            o.z = bcu(pkh(f1.x, f1.y));
            o.w = bcu(pkh(f1.z, f1.w));
            wlds[q * 512 + tid] = o;
        }
    }
    if (tid < 128) ((unsigned int*)hsh)[tid] = 0u;
    float c_state = 0.f;
    __syncthreads();

    const __fp16* gxb = gx2 + ((size_t)b * Tt * Hh + jj) * 4;  // step stride 1024 f16
    __fp16* hsb = hs16 + (size_t)b * Tt * Hh + jj;             // s=0 only

    float g0 = 0.f, g1 = 0.f, g2 = 0.f, g3 = 0.f;
    if (s == 0) {
        uint2 gv = *(const uint2*)gxb;
        half2_t p = bch(gv.x), q = bch(gv.y);
        g0 = (float)p[0]; g1 = (float)p[1]; g2 = (float)q[0]; g3 = (float)q[1];
    }

    const uint4* h4 = (const uint4*)hsh + (s << 4);  // 16 uint4 per K-half
    __fp16 hprev = (__fp16)0.f;

    for (int t = 0; t < Tt; ++t) {
        // deferred h store from step t-1 (keeps vmcnt drain off barrier-2)
        if (s == 0 && t > 0) hsb[(size_t)(t - 1) * Hh] = hprev;

        // prefetch next step's gx (independent of h)
        float n0 = 0.f, n1 = 0.f, n2 = 0.f, n3 = 0.f;
        if (s == 0) {
            const __fp16* gn = gxb + (size_t)(t + 1 < Tt ? t + 1 : t) * 1024;
            uint2 gv = *(const uint2*)gn;
            half2_t p = bch(gv.x), q = bch(gv.y);
            n0 = (float)p[0]; n1 = (float)p[1]; n2 = (float)q[0]; n3 = (float)q[1];
        }

        float a0 = 0.f, a1 = 0.f, a2 = 0.f, a3 = 0.f;

        #pragma unroll
        for (int q = 0; q < 16; ++q) {
            uint4 hv = h4[q];                     // uniform broadcast read (K-half)
            half2_t u0 = bch(hv.x), u1 = bch(hv.y);
            half2_t u2 = bch(hv.z), u3 = bch(hv.w);
            a0 = fdot2(w[0][q*4+0], u0, a0); a1 = fdot2(w[1][q*4+0], u0, a1);
            a2 = fdot2(w[2][q*4+0], u0, a2);
            a0 = fdot2(w[0][q*4+1], u1, a0); a1 = fdot2(w[1][q*4+1], u1, a1);
            a2 = fdot2(w[2][q*4+1], u1, a2);
            a0 = fdot2(w[0][q*4+2], u2, a0); a1 = fdot2(w[1][q*4+2], u2, a1);
            a2 = fdot2(w[2][q*4+2], u2, a2);
            a0 = fdot2(w[0][q*4+3], u3, a0); a1 = fdot2(w[1][q*4+3], u3, a1);
            a2 = fdot2(w[2][q*4+3], u3, a2);
            if (q < 8) {                          // gate-o pairs 0..31 from regs
                a3 = fdot2(wo[q*4+0], u0, a3);
                a3 = fdot2(wo[q*4+1], u1, a3);
                a3 = fdot2(wo[q*4+2], u2, a3);
                a3 = fdot2(wo[q*4+3], u3, a3);
            } else {                              // pairs 32..63 from LDS
                uint4 wv = wlds[(q - 8) * 512 + tid];
                a3 = fdot2(bch(wv.x), u0, a3);
                a3 = fdot2(bch(wv.y), u1, a3);
                a3 = fdot2(bch(wv.z), u2, a3);
                a3 = fdot2(bch(wv.w), u3, a3);
            }
        }

        if (s == 1) pex[jj] = make_float4(a0, a1, a2, a3);
        __syncthreads();                 // pex visible; all hsh reads complete

        if (s == 0) {
            float4 pp = pex[jj];
            float A0 = a0 + pp.x + g0;   // gate i
            float A1 = a1 + pp.y + g1;   // gate f
            float A2 = a2 + pp.z + g2;   // gate g
            float A3 = a3 + pp.w + g3;   // gate o
            float si = fsig(A0);
            float sf = fsig(A1);
            float tg = ftanh(A2);
            float so = fsig(A3);
            c_state = sf * c_state + si * tg;
            float hn = so * ftanh(c_state);
            hprev = (__fp16)hn;
            hsh[jj] = hprev;
        }
        g0 = n0; g1 = n1; g2 = n2; g3 = n3;
        __syncthreads();                 // h(t) visible for step t+1
    }
    if (s == 0) hsb[(size_t)(Tt - 1) * Hh] = hprev;
}

// ---------------- Kernel C: head via MFMA f16 -----------------------------------
__global__ __launch_bounds__(256) void head_mfma(const __fp16* __restrict__ hs16,
                                                 const __fp16* __restrict__ hw16,
                                                 const float* __restrict__ hb,
                                                 float* __restrict__ out) {
    const int tid = threadIdx.x;
    const int w = tid >> 6, l = tid & 63;
    const int mb = blockIdx.x * 64 + w * 16;
    const int n0 = blockIdx.y * 64;                  // 4 N-tiles of 16
    const int lr = l & 15, lk = l >> 4;

    f32x4 acc[4] = {};
    const __fp16* aa = hs16 + (size_t)(mb + lr) * Hh + lk * 8;
    #pragma unroll
    for (int ks = 0; ks < 8; ++ks) {                 // K=256, 32 per step
        f16x8 af = *(const f16x8*)(aa + ks * 32);
        #pragma unroll
        for (int nt = 0; nt < 4; ++nt) {
            const __fp16* bb = hw16 + (size_t)(n0 + nt * 16 + lr) * Hh + ks * 32 + lk * 8;
            f16x8 bf = *(const f16x8*)bb;
            acc[nt] = __builtin_amdgcn_mfma_f32_16x16x32_f16(af, bf, acc[nt], 0, 0, 0);
        }
    }
    #pragma unroll
    for (int nt = 0; nt < 4; ++nt) {
        int nv = n0 + nt * 16 + lr;
        int nh = nv >> 7, v = nv & 127;
        float bv = hb[nv];
        #pragma unroll
        for (int r = 0; r < 4; ++r) {
            int m = mb + lk * 4 + r;
            out[(size_t)nh * BT * Vv + (size_t)m * Vv + v] = acc[nt][r] + bv;
        }
    }
}

extern "C" void kernel_launch(void* const* d_in, const int* in_sizes, int n_in,
                              void* d_out, int out_size, void* d_ws, size_t ws_size,
                              hipStream_t stream) {
    const float* x    = (const float*)d_in[0];
    const float* Wih  = (const float*)d_in[1];
    const float* Whh  = (const float*)d_in[2];
    const float* bih  = (const float*)d_in[3];
    const float* bhh  = (const float*)d_in[4];
    const float* hw   = (const float*)d_in[5];
    const float* hb   = (const float*)d_in[6];
    float* out = (float*)d_out;

    // workspace carve (f16): hw16 | gx2 | hs16  (~160 MB total)
    __fp16* hw16 = (__fp16*)d_ws;                      // 384*256
    __fp16* gx2  = hw16 + (size_t)NVh * Vv * Hh;       // BT*1024 (packed f16x4)
    __fp16* hs16 = gx2 + (size_t)BT * G4;              // BT*256

    cvt16<<<(NVh * Vv * Hh / 4 + 255) / 256, 256, 0, stream>>>(hw, hw16, NVh * Vv * Hh / 4);
    gx_mfma<<<dim3(BT / 64, Hh / 16), 256, 0, stream>>>(x, Wih, bih, bhh, gx2);
    lstm_scan<<<Bb, 512, 0, stream>>>(gx2, Whh, hs16);
    head_mfma<<<dim3(BT / 64, (NVh * Vv) / 64), 256, 0, stream>>>(hs16, hw16, hb, out);
}

// Round 11
// 1755.166 us; speedup vs baseline: 1.0743x; 1.0743x over previous
//
#include <hip/hip_runtime.h>
#include <hip/hip_bf16.h>
#include <math.h>

#define Bb 64
#define Tt 1024
#define Dd 128
#define Hh 256
#define G4 1024  // 4*H
#define Vv 128
#define NVh 3
#define BT (Bb*Tt)

typedef __fp16 half2_t __attribute__((ext_vector_type(2)));
typedef __fp16 f16x4 __attribute__((ext_vector_type(4)));
typedef __fp16 f16x8 __attribute__((ext_vector_type(8)));
typedef float f32x4 __attribute__((ext_vector_type(4)));

__device__ __forceinline__ half2_t pkh(float a, float b) {
    return __builtin_amdgcn_cvt_pkrtz(a, b);
}
__device__ __forceinline__ float fdot2(half2_t a, half2_t b, float c) {
#if __has_builtin(__builtin_amdgcn_fdot2)
    return __builtin_amdgcn_fdot2(a, b, c, false);
#else
    return c + (float)a[0] * (float)b[0] + (float)a[1] * (float)b[1];
#endif
}
__device__ __forceinline__ half2_t bch(unsigned int x) {
    return __builtin_bit_cast(half2_t, x);
}
__device__ __forceinline__ unsigned int bcu(half2_t x) {
    return __builtin_bit_cast(unsigned int, x);
}
__device__ __forceinline__ float fsig(float x) {
    return __builtin_amdgcn_rcpf(1.f + __expf(-x));
}
__device__ __forceinline__ float ftanh(float x) {
    float e = __expf(-2.f * fabsf(x));
    float r = (1.f - e) * __builtin_amdgcn_rcpf(1.f + e);
    return copysignf(r, x);
}

// ---------------- Kernel 0: f32 -> f16 convert (RNE), n multiple of 4 ----------
__global__ __launch_bounds__(256) void cvt16(const float* __restrict__ in,
                                             __fp16* __restrict__ out, int n4) {
    int i = blockIdx.x * 256 + threadIdx.x;
    if (i < n4) {
        float4 v = ((const float4*)in)[i];
        f16x4 o;
        o[0] = (__fp16)v.x; o[1] = (__fp16)v.y;
        o[2] = (__fp16)v.z; o[3] = (__fp16)v.w;
        ((f16x4*)out)[i] = o;
    }
}

// ---------------- Kernel A: gx via MFMA f16 (R8 form) ----------------------------
// gx2[bt][jj][gate] (f16x4 packed) = x[bt][:]·W_ih[gate*256+jj][:] + b_ih + b_hh
__global__ __launch_bounds__(256) void gx_mfma(const __fp16* __restrict__ x16,
                                               const __fp16* __restrict__ Wih16,
                                               const float* __restrict__ bih,
                                               const float* __restrict__ bhh,
                                               __fp16* __restrict__ gx2) {
    const int tid = threadIdx.x;
    const int w = tid >> 6, l = tid & 63;
    const int mb = blockIdx.x * 64 + w * 16;
    const int jj0 = blockIdx.y * 16;
    const int lr = l & 15, lk = l >> 4;

    f32x4 acc[4] = {};
    const __fp16* xa = x16 + (size_t)(mb + lr) * Dd + lk * 8;
    #pragma unroll
    for (int ks = 0; ks < 4; ++ks) {                 // K=128, 32 per step
        f16x8 af = *(const f16x8*)(xa + ks * 32);
        #pragma unroll
        for (int g = 0; g < 4; ++g) {
            const __fp16* bb = Wih16 + (size_t)(g * 256 + jj0 + lr) * Dd + ks * 32 + lk * 8;
            f16x8 bf = *(const f16x8*)bb;
            acc[g] = __builtin_amdgcn_mfma_f32_16x16x32_f16(af, bf, acc[g], 0, 0, 0);
        }
    }
    float bsum[4];
    #pragma unroll
    for (int g = 0; g < 4; ++g) {
        int j = g * 256 + jj0 + lr;
        bsum[g] = bih[j] + bhh[j];
    }
    #pragma unroll
    for (int r = 0; r < 4; ++r) {
        int m = mb + lk * 4 + r;                     // D row = (lane>>4)*4+reg
        f16x4 o;
        o[0] = (__fp16)(acc[0][r] + bsum[0]);
        o[1] = (__fp16)(acc[1][r] + bsum[1]);
        o[2] = (__fp16)(acc[2][r] + bsum[2]);
        o[3] = (__fp16)(acc[3][r] + bsum[3]);
        *(f16x4*)&gx2[((size_t)m * Hh + jj0 + lr) * 4] = o;
    }
}

// ---------------- Kernel B: persistent LSTM scan (v10: R8 + 4-deep LDS prefetch) --
// 512 thr (8 waves, 2/SIMD). Thread (jj=tid&255, s=tid>>8): all 4 gate rows of
// h-index jj, K-half s. Gates i,f,g: w[3][64] = 192 reg pairs; gate o: 64 pairs
// in 128KB LDS. NEW: explicit 4-deep rolling prefetch of h-broadcast (hbuf) and
// W-tail (wbuf) ds_reads — issue at q, consume at q+4 (~128 cyc of fdot2 between)
// so LDS latency is covered by construction instead of relying on regalloc slack.
__global__ __launch_bounds__(512, 2) void lstm_scan(const __fp16* __restrict__ gx2,
                                                    const float* __restrict__ Whh,
                                                    __fp16* __restrict__ hs16) {
    __shared__ __align__(16) uint4 wlds[16 * 512];   // 128KB: [q][tid]
    __shared__ __align__(16) __fp16 hsh[Hh];         // 512B
    __shared__ __align__(16) float4 pex[256];        // 4KB: s=1 partials
    const int tid = threadIdx.x;
    const int jj = tid & 255;
    const int s = tid >> 8;            // wave-uniform (waves 0-3: s=0, 4-7: s=1)
    const int b = blockIdx.x;

    // ---- stage W: gates i,f,g K-half s into regs; gate o (64 pairs) into LDS ----
    half2_t w[3][64];
    #pragma unroll
    for (int g = 0; g < 3; ++g) {
        const float* wr = Whh + (size_t)(g * 256 + jj) * Hh + s * 128;
        #pragma unroll
        for (int c = 0; c < 16; ++c) {
            float4 f0 = *(const float4*)&wr[c * 8];
            float4 f1 = *(const float4*)&wr[c * 8 + 4];
            w[g][c*4+0] = pkh(f0.x, f0.y);
            w[g][c*4+1] = pkh(f0.z, f0.w);
            w[g][c*4+2] = pkh(f1.x, f1.y);
            w[g][c*4+3] = pkh(f1.z, f1.w);
        }
    }
    {
        const float* wr3 = Whh + (size_t)(3 * 256 + jj) * Hh + s * 128;
        #pragma unroll
        for (int q = 0; q < 16; ++q) {
            float4 f0 = *(const float4*)&wr3[q * 8];
            float4 f1 = *(const float4*)&wr3[q * 8 + 4];
            uint4 o;
            o.x = bcu(pkh(f0.x, f0.y));
            o.y = bcu(pkh(f0.z, f0.w));
            o.z = bcu(pkh(f1.x, f1.y));
            o.w = bcu(pkh(f1.z, f1.w));
            wlds[q * 512 + tid] = o;
        }
    }
    if (tid < 128) ((unsigned int*)hsh)[tid] = 0u;
    float c_state = 0.f;
    __syncthreads();

    const __fp16* gxb = gx2 + ((size_t)b * Tt * Hh + jj) * 4;  // step stride 1024 f16
    __fp16* hsb = hs16 + (size_t)b * Tt * Hh + jj;             // s=0 only

    float g0 = 0.f, g1 = 0.f, g2 = 0.f, g3 = 0.f;
    if (s == 0) {
        uint2 gv = *(const uint2*)gxb;
        half2_t p = bch(gv.x), q = bch(gv.y);
        g0 = (float)p[0]; g1 = (float)p[1]; g2 = (float)q[0]; g3 = (float)q[1];
    }

    const uint4* h4 = (const uint4*)hsh + (s << 4);  // 16 uint4 per K-half
    __fp16 hprev = (__fp16)0.f;

    for (int t = 0; t < Tt; ++t) {
        // deferred h store from step t-1 (keeps vmcnt drain off barrier-2)
        if (s == 0 && t > 0) hsb[(size_t)(t - 1) * Hh] = hprev;

        // prefetch next step's gx (independent of h)
        float n0 = 0.f, n1 = 0.f, n2 = 0.f, n3 = 0.f;
        if (s == 0) {
            const __fp16* gn = gxb + (size_t)(t + 1 < Tt ? t + 1 : t) * 1024;
            uint2 gv = *(const uint2*)gn;
            half2_t p = bch(gv.x), q = bch(gv.y);
            n0 = (float)p[0]; n1 = (float)p[1]; n2 = (float)q[0]; n3 = (float)q[1];
        }

        float a0 = 0.f, a1 = 0.f, a2 = 0.f, a3 = 0.f;

        // ---- prime the 4-deep prefetch pipeline ----
        uint4 hbuf[4], wbuf[4];
        #pragma unroll
        for (int p = 0; p < 4; ++p) {
            hbuf[p] = h4[p];
            wbuf[p] = wlds[p * 512 + tid];
        }

        #pragma unroll
        for (int q = 0; q < 16; ++q) {
            uint4 hv = hbuf[q & 3];
            uint4 wv = wbuf[q & 3];
            if (q < 12) {                         // issue loads 4 iterations ahead
                hbuf[q & 3] = h4[q + 4];
                wbuf[q & 3] = wlds[(q + 4) * 512 + tid];
            }
            half2_t u0 = bch(hv.x), u1 = bch(hv.y);
            half2_t u2 = bch(hv.z), u3 = bch(hv.w);
            a0 = fdot2(w[0][q*4+0], u0, a0); a1 = fdot2(w[1][q*4+0], u0, a1);
            a2 = fdot2(w[2][q*4+0], u0, a2); a3 = fdot2(bch(wv.x), u0, a3);
            a0 = fdot2(w[0][q*4+1], u1, a0); a1 = fdot2(w[1][q*4+1], u1, a1);
            a2 = fdot2(w[2][q*4+1], u1, a2); a3 = fdot2(bch(wv.y), u1, a3);
            a0 = fdot2(w[0][q*4+2], u2, a0); a1 = fdot2(w[1][q*4+2], u2, a1);
            a2 = fdot2(w[2][q*4+2], u2, a2); a3 = fdot2(bch(wv.z), u2, a3);
            a0 = fdot2(w[0][q*4+3], u3, a0); a1 = fdot2(w[1][q*4+3], u3, a1);
            a2 = fdot2(w[2][q*4+3], u3, a2); a3 = fdot2(bch(wv.w), u3, a3);
        }

        if (s == 1) pex[jj] = make_float4(a0, a1, a2, a3);
        __syncthreads();                 // pex visible; all hsh reads complete

        if (s == 0) {
            float4 pp = pex[jj];
            float A0 = a0 + pp.x + g0;   // gate i
            float A1 = a1 + pp.y + g1;   // gate f
            float A2 = a2 + pp.z + g2;   // gate g
            float A3 = a3 + pp.w + g3;   // gate o
            float si = fsig(A0);
            float sf = fsig(A1);
            float tg = ftanh(A2);
            float so = fsig(A3);
            c_state = sf * c_state + si * tg;
            float hn = so * ftanh(c_state);
            hprev = (__fp16)hn;
            hsh[jj] = hprev;
        }
        g0 = n0; g1 = n1; g2 = n2; g3 = n3;
        __syncthreads();                 // h(t) visible for step t+1
    }
    if (s == 0) hsb[(size_t)(Tt - 1) * Hh] = hprev;
}

// ---------------- Kernel C: head via MFMA f16 -----------------------------------
__global__ __launch_bounds__(256) void head_mfma(const __fp16* __restrict__ hs16,
                                                 const __fp16* __restrict__ hw16,
                                                 const float* __restrict__ hb,
                                                 float* __restrict__ out) {
    const int tid = threadIdx.x;
    const int w = tid >> 6, l = tid & 63;
    const int mb = blockIdx.x * 64 + w * 16;
    const int n0 = blockIdx.y * 64;                  // 4 N-tiles of 16
    const int lr = l & 15, lk = l >> 4;

    f32x4 acc[4] = {};
    const __fp16* aa = hs16 + (size_t)(mb + lr) * Hh + lk * 8;
    #pragma unroll
    for (int ks = 0; ks < 8; ++ks) {                 // K=256, 32 per step
        f16x8 af = *(const f16x8*)(aa + ks * 32);
        #pragma unroll
        for (int nt = 0; nt < 4; ++nt) {
            const __fp16* bb = hw16 + (size_t)(n0 + nt * 16 + lr) * Hh + ks * 32 + lk * 8;
            f16x8 bf = *(const f16x8*)bb;
            acc[nt] = __builtin_amdgcn_mfma_f32_16x16x32_f16(af, bf, acc[nt], 0, 0, 0);
        }
    }
    #pragma unroll
    for (int nt = 0; nt < 4; ++nt) {
        int nv = n0 + nt * 16 + lr;
        int nh = nv >> 7, v = nv & 127;
        float bv = hb[nv];
        #pragma unroll
        for (int r = 0; r < 4; ++r) {
            int m = mb + lk * 4 + r;
            out[(size_t)nh * BT * Vv + (size_t)m * Vv + v] = acc[nt][r] + bv;
        }
    }
}

extern "C" void kernel_launch(void* const* d_in, const int* in_sizes, int n_in,
                              void* d_out, int out_size, void* d_ws, size_t ws_size,
                              hipStream_t stream) {
    const float* x    = (const float*)d_in[0];
    const float* Wih  = (const float*)d_in[1];
    const float* Whh  = (const float*)d_in[2];
    const float* bih  = (const float*)d_in[3];
    const float* bhh  = (const float*)d_in[4];
    const float* hw   = (const float*)d_in[5];
    const float* hb   = (const float*)d_in[6];
    float* out = (float*)d_out;

    // workspace carve (f16): x16 | Wih16 | hw16 | gx2 | hs16  (~176 MB total)
    __fp16* x16   = (__fp16*)d_ws;                     // BT*128
    __fp16* Wih16 = x16 + (size_t)BT * Dd;             // 1024*128
    __fp16* hw16  = Wih16 + (size_t)G4 * Dd;           // 384*256
    __fp16* gx2   = hw16 + (size_t)NVh * Vv * Hh;      // BT*1024 (packed f16x4)
    __fp16* hs16  = gx2 + (size_t)BT * G4;             // BT*256

    cvt16<<<(BT * Dd / 4 + 255) / 256, 256, 0, stream>>>(x, x16, BT * Dd / 4);
    cvt16<<<(G4 * Dd / 4 + 255) / 256, 256, 0, stream>>>(Wih, Wih16, G4 * Dd / 4);
    cvt16<<<(NVh * Vv * Hh / 4 + 255) / 256, 256, 0, stream>>>(hw, hw16, NVh * Vv * Hh / 4);

    gx_mfma<<<dim3(BT / 64, Hh / 16), 256, 0, stream>>>(x16, Wih16, bih, bhh, gx2);
    lstm_scan<<<Bb, 512, 0, stream>>>(gx2, Whh, hs16);
    head_mfma<<<dim3(BT / 64, (NVh * Vv) / 64), 256, 0, stream>>>(hs16, hw16, hb, out);
}